// Round 1
// baseline (330.584 us; speedup 1.0000x reference)
//
#include <hip/hip_runtime.h>
#include <hip/hip_bf16.h>

typedef __attribute__((ext_vector_type(8))) short short8;
typedef __attribute__((ext_vector_type(4))) float f32x4;

static constexpr int Bb = 2, Tt = 2048, Cc = 1024, Hh = 16;
static constexpr int BT = Bb * Tt;     // 4096
static constexpr int N1 = 3 * Cc;      // 3072

__device__ __forceinline__ unsigned short f2b(float f) {
  union { float f; unsigned u; } v; v.f = f;
  unsigned r = v.u + 0x7fffu + ((v.u >> 16) & 1u);
  return (unsigned short)(r >> 16);
}
__device__ __forceinline__ float b2f(short s) {
  union { unsigned u; float f; } v; v.u = ((unsigned)(unsigned short)s) << 16;
  return v.f;
}

// ---------------- cast f32 -> bf16, 8 elems/thread ----------------
__global__ __launch_bounds__(256) void k_cast(const float* __restrict__ in,
                                              unsigned short* __restrict__ out, int n) {
  int i = (blockIdx.x * 256 + threadIdx.x) * 8;
  if (i >= n) return;
  float4 a = *reinterpret_cast<const float4*>(in + i);
  float4 b = *reinterpret_cast<const float4*>(in + i + 4);
  short8 o;
  o[0] = f2b(a.x); o[1] = f2b(a.y); o[2] = f2b(a.z); o[3] = f2b(a.w);
  o[4] = f2b(b.x); o[5] = f2b(b.y); o[6] = f2b(b.z); o[7] = f2b(b.w);
  *reinterpret_cast<short8*>(out + i) = o;
}

// ------------- transpose + cast: in R x Ccol f32 -> out Ccol x R bf16 -------------
__global__ __launch_bounds__(256) void k_tcast(const float* __restrict__ in,
                                               unsigned short* __restrict__ out,
                                               int R, int Ccol) {
  __shared__ float tile[32][33];
  int cb = blockIdx.x * 32, rb = blockIdx.y * 32;
  int tx = threadIdx.x & 31, ty = threadIdx.x >> 5;  // ty 0..7
  for (int i = 0; i < 32; i += 8)
    tile[ty + i][tx] = in[(size_t)(rb + ty + i) * Ccol + cb + tx];
  __syncthreads();
  for (int i = 0; i < 32; i += 8)
    out[(size_t)(cb + ty + i) * R + rb + tx] = f2b(tile[tx][ty + i]);
}

// ---------------- bf16 GEMM: C(MxN) = A(MxK) * Bt(NxK)^T + bias ----------------
// 128x128 tile, BK=64, 4 waves (2x2), 4x4 16x16x32 MFMA per wave. m97 structure.
template <int OUT_BF16>
__global__ __launch_bounds__(256)
void k_gemm(const unsigned short* __restrict__ A, const unsigned short* __restrict__ Bt,
            const float* __restrict__ bias, void* __restrict__ Cout,
            int M, int N, int K) {
  __shared__ unsigned short Al[128 * 64];
  __shared__ unsigned short Bl[128 * 64];
  const int tid = threadIdx.x;
  const int lane = tid & 63;
  const int w = tid >> 6;
  const int wm = w >> 1, wn = w & 1;
  const int mb = blockIdx.y, nb = blockIdx.x;
  const int l15 = lane & 15, l4 = lane >> 4;
  f32x4 acc[4][4] = {};

  const size_t arow0 = (size_t)mb * 128;
  const size_t brow0 = (size_t)nb * 128;

  for (int k0 = 0; k0 < K; k0 += 64) {
    __syncthreads();
#pragma unroll
    for (int cc = 0; cc < 4; cc++) {
      int c = w + cc * 4;                 // wave-uniform chunk id 0..15
      int e = c * 512 + lane * 8;         // bf16 element offset in 128x64 tile
      int row = e >> 6, col = e & 63;
      const unsigned short* ga = A + (arow0 + row) * (size_t)K + k0 + col;
      const unsigned short* gb = Bt + (brow0 + row) * (size_t)K + k0 + col;
      __builtin_amdgcn_global_load_lds((__attribute__((address_space(1))) void*)ga,
                                       (__attribute__((address_space(3))) void*)(Al + c * 512),
                                       16, 0, 0);
      __builtin_amdgcn_global_load_lds((__attribute__((address_space(1))) void*)gb,
                                       (__attribute__((address_space(3))) void*)(Bl + c * 512),
                                       16, 0, 0);
    }
    __syncthreads();
#pragma unroll
    for (int kc = 0; kc < 2; kc++) {
      short8 af[4], bfr[4];
#pragma unroll
      for (int m = 0; m < 4; m++)
        af[m] = *reinterpret_cast<const short8*>(&Al[(wm * 64 + m * 16 + l15) * 64 + kc * 32 + l4 * 8]);
#pragma unroll
      for (int n = 0; n < 4; n++)
        bfr[n] = *reinterpret_cast<const short8*>(&Bl[(wn * 64 + n * 16 + l15) * 64 + kc * 32 + l4 * 8]);
#pragma unroll
      for (int m = 0; m < 4; m++)
#pragma unroll
        for (int n = 0; n < 4; n++)
          acc[m][n] = __builtin_amdgcn_mfma_f32_16x16x32_bf16(af[m], bfr[n], acc[m][n], 0, 0, 0);
    }
  }

#pragma unroll
  for (int m = 0; m < 4; m++) {
#pragma unroll
    for (int n = 0; n < 4; n++) {
      int ccol = nb * 128 + wn * 64 + n * 16 + l15;
      float bv = bias ? bias[ccol] : 0.f;
#pragma unroll
      for (int j = 0; j < 4; j++) {
        int r = mb * 128 + wm * 64 + m * 16 + l4 * 4 + j;
        float v = acc[m][n][j] + bv;
        if (OUT_BF16)
          ((unsigned short*)Cout)[(size_t)r * N + ccol] = f2b(v);
        else
          ((float*)Cout)[(size_t)r * N + ccol] = v;
      }
    }
  }
}

// ---------------- RoPE + head relayout + V transpose ----------------
// qkv: (B*T, 3072) bf16. Outputs: Qs,Ks (B,H,T,64) bf16 (Q pre-scaled 1/8), Vt (B,H,64,T) bf16.
__global__ __launch_bounds__(256)
void k_rope(const unsigned short* __restrict__ qkv, const float* __restrict__ rope,
            unsigned short* __restrict__ Qs, unsigned short* __restrict__ Ks,
            unsigned short* __restrict__ Vt) {
  __shared__ unsigned short vt_l[64][72];  // 16B-aligned rows (144B stride)
  int bid = blockIdx.x;
  int tb = bid & 31, h = (bid >> 5) & 15, b = bid >> 9;
  int tid = threadIdx.x;
#pragma unroll
  for (int r = 0; r < 2; r++) {
    int e = (r * 256 + tid) * 8;
    int tl = e >> 6, d = e & 63;
    int t = tb * 64 + tl;
    const unsigned short* rowp = qkv + (size_t)(b * Tt + t) * 3072 + h * 64 + d;
    short8 qv = *reinterpret_cast<const short8*>(rowp);
    short8 kv = *reinterpret_cast<const short8*>(rowp + 1024);
    short8 vv = *reinterpret_cast<const short8*>(rowp + 2048);
    short8 qo, ko;
#pragma unroll
    for (int p = 0; p < 4; p++) {
      int j = (d >> 1) + p;
      float4 rv = *reinterpret_cast<const float4*>(rope + ((size_t)t * 32 + j) * 4);
      // rv = (cos, -sin, sin, cos)
      float xq = b2f(qv[2 * p]), yq = b2f(qv[2 * p + 1]);
      float xk = b2f(kv[2 * p]), yk = b2f(kv[2 * p + 1]);
      qo[2 * p]     = (short)f2b((xq * rv.x + yq * rv.y) * 0.125f);
      qo[2 * p + 1] = (short)f2b((xq * rv.z + yq * rv.w) * 0.125f);
      ko[2 * p]     = (short)f2b(xk * rv.x + yk * rv.y);
      ko[2 * p + 1] = (short)f2b(xk * rv.z + yk * rv.w);
    }
    size_t qdst = ((size_t)(b * 16 + h) * Tt + t) * 64 + d;
    *reinterpret_cast<short8*>(Qs + qdst) = qo;
    *reinterpret_cast<short8*>(Ks + qdst) = ko;
#pragma unroll
    for (int i2 = 0; i2 < 8; i2++) vt_l[d + i2][tl] = (unsigned short)vv[i2];
  }
  __syncthreads();
#pragma unroll
  for (int r = 0; r < 2; r++) {
    int e = (r * 256 + tid) * 8;
    int dl = e >> 6, tl = e & 63;
    short8 o = *reinterpret_cast<const short8*>(&vt_l[dl][tl]);
    *reinterpret_cast<short8*>(Vt + ((size_t)(b * 16 + h) * 64 + dl) * Tt + tb * 64 + tl) = o;
  }
}

// ---------------- causal flash attention ----------------
// Qs pre-scaled by 1/sqrt(64). 4 waves/block, 16 q-rows/wave, KV step 32.
__global__ __launch_bounds__(256)
void k_attn(const unsigned short* __restrict__ Qs, const unsigned short* __restrict__ Ks,
            const unsigned short* __restrict__ Vt, unsigned short* __restrict__ Y) {
  __shared__ unsigned short Pl[4][16 * 40];  // per-wave P tile, stride 40 (16B-aligned rows)
  int tid = threadIdx.x, lane = tid & 63, w = tid >> 6;
  int bid = blockIdx.x;
  int bh = bid >> 5, qb = bid & 31;
  int b = bh >> 4, h = bh & 15;
  int l15 = lane & 15, l4 = lane >> 4;
  int qw0 = qb * 64 + w * 16;
  const unsigned short* Qb = Qs + (size_t)bh * Tt * 64;
  const unsigned short* Kb = Ks + (size_t)bh * Tt * 64;
  const unsigned short* Vb = Vt + (size_t)bh * 64 * Tt;

  short8 q0 = *reinterpret_cast<const short8*>(Qb + (size_t)(qw0 + l15) * 64 + l4 * 8);
  short8 q1 = *reinterpret_cast<const short8*>(Qb + (size_t)(qw0 + l15) * 64 + 32 + l4 * 8);

  float m_run[4], l_run[4];
  f32x4 oacc[4] = {};
#pragma unroll
  for (int j = 0; j < 4; j++) { m_run[j] = -1e30f; l_run[j] = 0.f; }

  int kv_end = qw0 + 16;
  for (int kv0 = 0; kv0 < kv_end; kv0 += 32) {
    f32x4 st[2];
#pragma unroll
    for (int t2 = 0; t2 < 2; t2++) {
      const unsigned short* kp = Kb + (size_t)(kv0 + t2 * 16 + l15) * 64;
      short8 kf0 = *reinterpret_cast<const short8*>(kp + l4 * 8);
      short8 kf1 = *reinterpret_cast<const short8*>(kp + 32 + l4 * 8);
      f32x4 s = {};
      s = __builtin_amdgcn_mfma_f32_16x16x32_bf16(q0, kf0, s, 0, 0, 0);
      s = __builtin_amdgcn_mfma_f32_16x16x32_bf16(q1, kf1, s, 0, 0, 0);
      int col = kv0 + t2 * 16 + l15;
#pragma unroll
      for (int j = 0; j < 4; j++) {
        int rq = qw0 + l4 * 4 + j;
        if (col > rq) s[j] = -1e30f;
      }
      st[t2] = s;
    }
    float mx[4];
#pragma unroll
    for (int j = 0; j < 4; j++) mx[j] = fmaxf(st[0][j], st[1][j]);
#pragma unroll
    for (int off = 1; off < 16; off <<= 1)
#pragma unroll
      for (int j = 0; j < 4; j++) mx[j] = fmaxf(mx[j], __shfl_xor(mx[j], off));
    float fsc[4], psum[4];
#pragma unroll
    for (int j = 0; j < 4; j++) {
      float nm = fmaxf(m_run[j], mx[j]);
      fsc[j] = __expf(m_run[j] - nm);
      m_run[j] = nm;
      psum[j] = 0.f;
    }
#pragma unroll
    for (int t2 = 0; t2 < 2; t2++)
#pragma unroll
      for (int j = 0; j < 4; j++) {
        float p = __expf(st[t2][j] - m_run[j]);
        psum[j] += p;
        Pl[w][(l4 * 4 + j) * 40 + t2 * 16 + l15] = f2b(p);
      }
#pragma unroll
    for (int off = 1; off < 16; off <<= 1)
#pragma unroll
      for (int j = 0; j < 4; j++) psum[j] += __shfl_xor(psum[j], off);
#pragma unroll
    for (int j = 0; j < 4; j++) l_run[j] = l_run[j] * fsc[j] + psum[j];
#pragma unroll
    for (int n = 0; n < 4; n++)
#pragma unroll
      for (int j = 0; j < 4; j++) oacc[n][j] *= fsc[j];

    short8 pf = *reinterpret_cast<const short8*>(&Pl[w][l15 * 40 + l4 * 8]);
#pragma unroll
    for (int n = 0; n < 4; n++) {
      short8 vf = *reinterpret_cast<const short8*>(Vb + (size_t)(n * 16 + l15) * Tt + kv0 + l4 * 8);
      oacc[n] = __builtin_amdgcn_mfma_f32_16x16x32_bf16(pf, vf, oacc[n], 0, 0, 0);
    }
  }
  float inv[4];
#pragma unroll
  for (int j = 0; j < 4; j++) inv[j] = 1.0f / l_run[j];
#pragma unroll
  for (int n = 0; n < 4; n++)
#pragma unroll
    for (int j = 0; j < 4; j++) {
      int t = qw0 + l4 * 4 + j;
      Y[((size_t)b * Tt + t) * Cc + h * 64 + n * 16 + l15] = f2b(oacc[n][j] * inv[j]);
    }
}

extern "C" void kernel_launch(void* const* d_in, const int* in_sizes, int n_in,
                              void* d_out, int out_size, void* d_ws, size_t ws_size,
                              hipStream_t stream) {
  (void)in_sizes; (void)n_in; (void)out_size; (void)ws_size;
  const float* x      = (const float*)d_in[0];
  const float* W_attn = (const float*)d_in[1];
  const float* b_attn = (const float*)d_in[2];
  const float* W_proj = (const float*)d_in[3];
  const float* b_proj = (const float*)d_in[4];
  const float* rope   = (const float*)d_in[5];
  float* out = (float*)d_out;

  char* ws = (char*)d_ws;
  unsigned short* xb  = (unsigned short*)(ws);                     // 8 MB
  unsigned short* WaT = (unsigned short*)(ws + (8u << 20));        // 6 MB
  unsigned short* WpT = (unsigned short*)(ws + (14u << 20));       // 2 MB
  unsigned short* qkv = (unsigned short*)(ws + (16u << 20));       // 24 MB
  unsigned short* Qs  = (unsigned short*)(ws + (40u << 20));       // 8 MB
  unsigned short* Ks  = (unsigned short*)(ws + (48u << 20));       // 8 MB
  unsigned short* Vt  = (unsigned short*)(ws + (56u << 20));       // 8 MB
  unsigned short* Yb  = (unsigned short*)(ws + (64u << 20));       // 8 MB  (total 72 MB)

  k_cast<<<2048, 256, 0, stream>>>(x, xb, BT * Cc);
  k_tcast<<<dim3(N1 / 32, Cc / 32), 256, 0, stream>>>(W_attn, WaT, Cc, N1);
  k_tcast<<<dim3(Cc / 32, Cc / 32), 256, 0, stream>>>(W_proj, WpT, Cc, Cc);
  k_gemm<1><<<dim3(N1 / 128, BT / 128), 256, 0, stream>>>(xb, WaT, b_attn, qkv, BT, N1, Cc);
  k_rope<<<Bb * Hh * (Tt / 64), 256, 0, stream>>>(qkv, rope, Qs, Ks, Vt);
  k_attn<<<Bb * Hh * (Tt / 64), 256, 0, stream>>>(Qs, Ks, Vt, Yb);
  k_gemm<0><<<dim3(Cc / 128, BT / 128), 256, 0, stream>>>(Yb, WpT, b_proj, out, BT, Cc, Cc);
}